// Round 1
// baseline (345.869 us; speedup 1.0000x reference)
//
#include <hip/hip_runtime.h>

#define BS     8192
#define DIM    768
#define NPART  8
#define BM     128
#define BN     128
#define BK     64
#define PCOLS  (BS / NPART)     // 1024 cols per partition
#define NJT    (PCOLS / BN)     // 8 col-tiles per block
#define NKT    (DIM / BK)       // 12 k-tiles
#define LDSW   72               // 64 + 8 pad (bf16 elems) -> 144B row stride (36 banks)

typedef __bf16 bfrag_t __attribute__((ext_vector_type(8)));
typedef float  facc_t  __attribute__((ext_vector_type(4)));

__device__ __forceinline__ unsigned short f2bf(float f) {
  union { float f; unsigned u; } v; v.f = f;
  unsigned u = v.u;
  return (unsigned short)((u + 0x7FFFu + ((u >> 16) & 1u)) >> 16);  // RNE
}

// ---------------- fp32 -> bf16 pre-convert ----------------
__global__ void tobf16_kernel(const float* __restrict__ in, unsigned short* __restrict__ out) {
  int i = (blockIdx.x * blockDim.x + threadIdx.x) * 4;
  float4 v = *reinterpret_cast<const float4*>(in + i);
  ushort4 o;
  o.x = f2bf(v.x); o.y = f2bf(v.y); o.z = f2bf(v.z); o.w = f2bf(v.w);
  *reinterpret_cast<ushort4*>(out + i) = o;
}

// ---------------- diag[i] = <nl[i], code[i]> in fp32 ----------------
__global__ void diag_kernel(const float* __restrict__ a, const float* __restrict__ b,
                            float* __restrict__ dg) {
  int lane = threadIdx.x & 63;
  int wave = threadIdx.x >> 6;
  int row  = blockIdx.x * 4 + wave;
  const float4* ar = reinterpret_cast<const float4*>(a + (size_t)row * DIM);
  const float4* br = reinterpret_cast<const float4*>(b + (size_t)row * DIM);
  float s = 0.f;
#pragma unroll
  for (int i = 0; i < 3; ++i) {                 // 768/4 = 192 float4, 3 per lane
    float4 x = ar[lane + 64 * i];
    float4 y = br[lane + 64 * i];
    s += x.x * y.x + x.y * y.y + x.z * y.z + x.w * y.w;
  }
#pragma unroll
  for (int off = 32; off; off >>= 1) s += __shfl_xor(s, off, 64);
  if (lane == 0) dg[row] = s;
}

// ---------------- fused GEMM (bf16 MFMA) + online row-wise logsumexp ----------------
// block: 256 threads (4 waves, 2x2 of 64x64), tile 128x128, BK=64.
// grid: (NPART, BS/BM). Each block covers rows [rb*128,+128), cols [cp*1024,+1024),
// emits partial (m,l) per row for its partition.
__global__ void gemm_lse_kernel(const unsigned short* __restrict__ Abf,
                                const unsigned short* __restrict__ Bbf,
                                float* __restrict__ pm, float* __restrict__ pl) {
  __shared__ __align__(16) unsigned short As[BM * LDSW];
  __shared__ __align__(16) unsigned short Bs[BN * LDSW];
  __shared__ float cm[2][BM];
  __shared__ float cl[2][BM];

  const int tid  = threadIdx.x;
  const int lane = tid & 63;
  const int wave = tid >> 6;
  const int wm   = wave >> 1;     // row half of the 128x128 tile
  const int wn   = wave & 1;      // col half
  const int l15  = lane & 15;
  const int l4   = lane >> 4;
  const int cp   = blockIdx.x;
  const int rb   = blockIdx.y;

  // per-lane online-lse state: 16 rows (4 m-tiles x 4 regs), lane's own column subset
  float mrun[4][4], lrun[4][4];
#pragma unroll
  for (int i = 0; i < 4; ++i)
#pragma unroll
    for (int r = 0; r < 4; ++r) { mrun[i][r] = -1e30f; lrun[i][r] = 0.f; }

  for (int jt = 0; jt < NJT; ++jt) {
    facc_t acc[4][4];
#pragma unroll
    for (int mt = 0; mt < 4; ++mt)
#pragma unroll
      for (int nt = 0; nt < 4; ++nt) acc[mt][nt] = (facc_t){0.f, 0.f, 0.f, 0.f};

    for (int kt = 0; kt < NKT; ++kt) {
      __syncthreads();
      // stage A & B tiles (128x64 bf16 each): 1024 16B-units each, 4/thread
#pragma unroll
      for (int i = 0; i < 4; ++i) {
        int u   = tid + i * 256;        // 0..1023
        int row = u >> 3;               // 8 units of 8 bf16 per 64-elem row
        int c8  = u & 7;
        uint4 va = *reinterpret_cast<const uint4*>(
            Abf + (size_t)(rb * BM + row) * DIM + kt * BK + c8 * 8);
        *reinterpret_cast<uint4*>(&As[row * LDSW + c8 * 8]) = va;
        uint4 vb = *reinterpret_cast<const uint4*>(
            Bbf + (size_t)(cp * PCOLS + jt * BN + row) * DIM + kt * BK + c8 * 8);
        *reinterpret_cast<uint4*>(&Bs[row * LDSW + c8 * 8]) = vb;
      }
      __syncthreads();

#pragma unroll
      for (int ks = 0; ks < 2; ++ks) {
        const int koff = ks * 32 + l4 * 8;
        bfrag_t af[4], bfv[4];
#pragma unroll
        for (int mt = 0; mt < 4; ++mt)
          af[mt] = *reinterpret_cast<const bfrag_t*>(&As[(wm * 64 + mt * 16 + l15) * LDSW + koff]);
#pragma unroll
        for (int nt = 0; nt < 4; ++nt)
          bfv[nt] = *reinterpret_cast<const bfrag_t*>(&Bs[(wn * 64 + nt * 16 + l15) * LDSW + koff]);
#pragma unroll
        for (int mt = 0; mt < 4; ++mt)
#pragma unroll
          for (int nt = 0; nt < 4; ++nt)
            acc[mt][nt] = __builtin_amdgcn_mfma_f32_16x16x32_bf16(af[mt], bfv[nt], acc[mt][nt], 0, 0, 0);
      }
    }

    // online-lse update (per lane, no cross-lane traffic)
#pragma unroll
    for (int mt = 0; mt < 4; ++mt)
#pragma unroll
      for (int r = 0; r < 4; ++r) {
        float v0 = acc[mt][0][r], v1 = acc[mt][1][r], v2 = acc[mt][2][r], v3 = acc[mt][3][r];
        float tm = fmaxf(fmaxf(v0, v1), fmaxf(v2, v3));
        float mn = fmaxf(mrun[mt][r], tm);
        float sc = __expf(mrun[mt][r] - mn);
        lrun[mt][r] = lrun[mt][r] * sc +
                      __expf(v0 - mn) + __expf(v1 - mn) + __expf(v2 - mn) + __expf(v3 - mn);
        mrun[mt][r] = mn;
      }
  }

  // merge across the 16 lanes of each quad-group (different column subsets, same rows)
#pragma unroll
  for (int mask = 1; mask < 16; mask <<= 1)
#pragma unroll
    for (int mt = 0; mt < 4; ++mt)
#pragma unroll
      for (int r = 0; r < 4; ++r) {
        float om = __shfl_xor(mrun[mt][r], mask, 64);
        float ol = __shfl_xor(lrun[mt][r], mask, 64);
        float mn = fmaxf(mrun[mt][r], om);
        lrun[mt][r] = lrun[mt][r] * __expf(mrun[mt][r] - mn) + ol * __expf(om - mn);
        mrun[mt][r] = mn;
      }

  __syncthreads();
  if (l15 == 0) {
#pragma unroll
    for (int mt = 0; mt < 4; ++mt)
#pragma unroll
      for (int r = 0; r < 4; ++r) {
        int rl = wm * 64 + mt * 16 + l4 * 4 + r;
        cm[wn][rl] = mrun[mt][r];
        cl[wn][rl] = lrun[mt][r];
      }
  }
  __syncthreads();
  if (tid < BM) {
    float m0 = cm[0][tid], l0 = cl[0][tid];
    float m1 = cm[1][tid], l1 = cl[1][tid];
    float mn = fmaxf(m0, m1);
    float ll = l0 * __expf(m0 - mn) + l1 * __expf(m1 - mn);
    size_t g = (size_t)(rb * BM + tid) * NPART + cp;
    pm[g] = mn;
    pl[g] = ll;
  }
}

// ---------------- combine partitions, subtract diag, mean -> loss ----------------
__global__ void loss_kernel(const float* __restrict__ pm, const float* __restrict__ pl,
                            const float* __restrict__ dg, float* __restrict__ out) {
  __shared__ float red[1024];
  int tid = threadIdx.x;
  float local = 0.f;
  for (int j = 0; j < BS / 1024; ++j) {
    int r = tid + j * 1024;
    float m = -1e30f, l = 0.f;
#pragma unroll
    for (int p = 0; p < NPART; ++p) {
      float m2 = pm[(size_t)r * NPART + p];
      float l2 = pl[(size_t)r * NPART + p];
      float mn = fmaxf(m, m2);
      l = l * __expf(m - mn) + l2 * __expf(m2 - mn);
      m = mn;
    }
    local += m + __logf(l) - dg[r];
  }
  red[tid] = local;
  __syncthreads();
  for (int s = 512; s; s >>= 1) {
    if (tid < s) red[tid] += red[tid + s];
    __syncthreads();
  }
  if (tid == 0) out[0] = red[0] / (float)BS;
}

extern "C" void kernel_launch(void* const* d_in, const int* in_sizes, int n_in,
                              void* d_out, int out_size, void* d_ws, size_t ws_size,
                              hipStream_t stream) {
  const float* nl = (const float*)d_in[0];
  const float* cd = (const float*)d_in[1];
  float* out = (float*)d_out;

  const size_t NEL = (size_t)BS * DIM;  // 6291456

  // workspace layout
  unsigned short* nlb = (unsigned short*)d_ws;       // NEL bf16
  unsigned short* cdb = nlb + NEL;                   // NEL bf16
  float* pm = (float*)(cdb + NEL);                   // BS*NPART
  float* pl = pm + (size_t)BS * NPART;               // BS*NPART
  float* dg = pl + (size_t)BS * NPART;               // BS

  // outputs 1,2: exact copies (loss, code_vec, nl_vec)
  hipMemcpyAsync(out + 1,       cd, NEL * sizeof(float), hipMemcpyDeviceToDevice, stream);
  hipMemcpyAsync(out + 1 + NEL, nl, NEL * sizeof(float), hipMemcpyDeviceToDevice, stream);

  tobf16_kernel<<<NEL / 4 / 256, 256, 0, stream>>>(nl, nlb);
  tobf16_kernel<<<NEL / 4 / 256, 256, 0, stream>>>(cd, cdb);
  diag_kernel<<<BS / 4, 256, 0, stream>>>(nl, cd, dg);
  gemm_lse_kernel<<<dim3(NPART, BS / BM), 256, 0, stream>>>(nlb, cdb, pm, pl);
  loss_kernel<<<1, 1024, 0, stream>>>(pm, pl, dg, out);
}

// Round 2
// 248.962 us; speedup vs baseline: 1.3892x; 1.3892x over previous
//
#include <hip/hip_runtime.h>

#define BS     8192
#define DIM    768
#define NPART  16
#define BM     128
#define BN     128
#define BK     64
#define PCOLS  (BS / NPART)     // 512 cols per partition
#define NJT    (PCOLS / BN)     // 4 col-tiles per block
#define NKT    (DIM / BK)       // 12 k-tiles

typedef __bf16 bfrag_t __attribute__((ext_vector_type(8)));
typedef float  facc_t  __attribute__((ext_vector_type(4)));

typedef const __attribute__((address_space(1))) void gv_t;
typedef __attribute__((address_space(3))) void lv_t;

__device__ __forceinline__ void gll16(const void* g, void* l) {
  // async global->LDS DMA, 16B/lane; LDS dest = wave-uniform base + lane*16
  __builtin_amdgcn_global_load_lds((gv_t*)g, (lv_t*)l, 16, 0, 0);
}

__device__ __forceinline__ unsigned short f2bf(float f) {
  union { float f; unsigned u; } v; v.f = f;
  unsigned u = v.u;
  return (unsigned short)((u + 0x7FFFu + ((u >> 16) & 1u)) >> 16);  // RNE
}

// ---------------- fp32 copy-out + bf16 convert in one pass ----------------
__global__ void prep_kernel(const float* __restrict__ in, float* __restrict__ outcopy,
                            unsigned short* __restrict__ outbf) {
  int i = (blockIdx.x * blockDim.x + threadIdx.x) * 4;
  float4 v = *reinterpret_cast<const float4*>(in + i);
  *reinterpret_cast<float4*>(outcopy + i) = v;
  ushort4 o;
  o.x = f2bf(v.x); o.y = f2bf(v.y); o.z = f2bf(v.z); o.w = f2bf(v.w);
  *reinterpret_cast<ushort4*>(outbf + i) = o;
}

// ---------------- diag[i] = <nl[i], code[i]> in fp32 ----------------
__global__ void diag_kernel(const float* __restrict__ a, const float* __restrict__ b,
                            float* __restrict__ dg) {
  int lane = threadIdx.x & 63;
  int wave = threadIdx.x >> 6;
  int row  = blockIdx.x * 4 + wave;
  const float4* ar = reinterpret_cast<const float4*>(a + (size_t)row * DIM);
  const float4* br = reinterpret_cast<const float4*>(b + (size_t)row * DIM);
  float s = 0.f;
#pragma unroll
  for (int i = 0; i < 3; ++i) {
    float4 x = ar[lane + 64 * i];
    float4 y = br[lane + 64 * i];
    s += x.x * y.x + x.y * y.y + x.z * y.z + x.w * y.w;
  }
#pragma unroll
  for (int off = 32; off; off >>= 1) s += __shfl_xor(s, off, 64);
  if (lane == 0) dg[row] = s;
}

// ---------------- fused GEMM (bf16 MFMA, global_load_lds staging) + online lse ----------------
// block: 256 threads (4 waves, 2x2 of 64x64), tile 128x128, BK=64.
// grid: (NPART, BS/BM) = (16, 64) = 1024 blocks = 4/CU.
// LDS: XOR-swizzled, unpadded (required by global_load_lds):
//   unit u (16B = 8 bf16) holds global (row=u>>3, c8 = (u&7)^(row&7)).
__global__ __launch_bounds__(256, 4) void gemm_lse_kernel(
    const unsigned short* __restrict__ Abf,
    const unsigned short* __restrict__ Bbf,
    float* __restrict__ pm, float* __restrict__ pl) {
  __shared__ __align__(16) unsigned short As[BM * BK];   // 16 KB
  __shared__ __align__(16) unsigned short Bs[BN * BK];   // 16 KB

  const int tid  = threadIdx.x;
  const int lane = tid & 63;
  const int wave = tid >> 6;
  const int wm   = wave >> 1;
  const int wn   = wave & 1;
  const int l15  = lane & 15;
  const int l4   = lane >> 4;
  const int sw   = l15 & 7;        // row-dependent xor for fragment reads
  const int cp   = blockIdx.x;
  const int rb   = blockIdx.y;

  // staging geometry (kt-invariant): per instr t, u = wave*256 + t*64 + lane
  int srow[4], sc8g[4];
#pragma unroll
  for (int t = 0; t < 4; ++t) {
    int u   = wave * 256 + t * 64 + lane;
    srow[t] = u >> 3;
    sc8g[t] = (u & 7) ^ (srow[t] & 7);
  }

  float mrun[4][4], lrun[4][4];
#pragma unroll
  for (int i = 0; i < 4; ++i)
#pragma unroll
    for (int r = 0; r < 4; ++r) { mrun[i][r] = -1e30f; lrun[i][r] = 0.f; }

  for (int jt = 0; jt < NJT; ++jt) {
    facc_t acc[4][4];
#pragma unroll
    for (int mt = 0; mt < 4; ++mt)
#pragma unroll
      for (int nt = 0; nt < 4; ++nt) acc[mt][nt] = (facc_t){0.f, 0.f, 0.f, 0.f};

    for (int kt = 0; kt < NKT; ++kt) {
      __syncthreads();
#pragma unroll
      for (int t = 0; t < 4; ++t) {
        size_t ldso = (size_t)(wave * 256 + t * 64) * 8;  // shorts
        gll16(Abf + (size_t)(rb * BM + srow[t]) * DIM + kt * BK + sc8g[t] * 8, As + ldso);
        gll16(Bbf + (size_t)(cp * PCOLS + jt * BN + srow[t]) * DIM + kt * BK + sc8g[t] * 8, Bs + ldso);
      }
      __syncthreads();

#pragma unroll
      for (int ks = 0; ks < 2; ++ks) {
        const int k8 = ks * 4 + l4;
        bfrag_t af[4], bfv[4];
#pragma unroll
        for (int mt = 0; mt < 4; ++mt) {
          int row = wm * 64 + mt * 16 + l15;
          af[mt] = *reinterpret_cast<const bfrag_t*>(&As[row * BK + (k8 ^ sw) * 8]);
        }
#pragma unroll
        for (int nt = 0; nt < 4; ++nt) {
          int row = wn * 64 + nt * 16 + l15;
          bfv[nt] = *reinterpret_cast<const bfrag_t*>(&Bs[row * BK + (k8 ^ sw) * 8]);
        }
#pragma unroll
        for (int mt = 0; mt < 4; ++mt)
#pragma unroll
          for (int nt = 0; nt < 4; ++nt)
            acc[mt][nt] = __builtin_amdgcn_mfma_f32_16x16x32_bf16(af[mt], bfv[nt], acc[mt][nt], 0, 0, 0);
      }
    }

    // online-lse update (per lane over its own column subset)
#pragma unroll
    for (int mt = 0; mt < 4; ++mt)
#pragma unroll
      for (int r = 0; r < 4; ++r) {
        float v0 = acc[mt][0][r], v1 = acc[mt][1][r], v2 = acc[mt][2][r], v3 = acc[mt][3][r];
        float tm = fmaxf(fmaxf(v0, v1), fmaxf(v2, v3));
        float mn = fmaxf(mrun[mt][r], tm);
        float sc = __expf(mrun[mt][r] - mn);
        lrun[mt][r] = lrun[mt][r] * sc +
                      __expf(v0 - mn) + __expf(v1 - mn) + __expf(v2 - mn) + __expf(v3 - mn);
        mrun[mt][r] = mn;
      }
  }

  // merge across the 16 lanes sharing rows (different column subsets)
#pragma unroll
  for (int mask = 1; mask < 16; mask <<= 1)
#pragma unroll
    for (int mt = 0; mt < 4; ++mt)
#pragma unroll
      for (int r = 0; r < 4; ++r) {
        float om = __shfl_xor(mrun[mt][r], mask, 64);
        float ol = __shfl_xor(lrun[mt][r], mask, 64);
        float mn = fmaxf(mrun[mt][r], om);
        lrun[mt][r] = lrun[mt][r] * __expf(mrun[mt][r] - mn) + ol * __expf(om - mn);
        mrun[mt][r] = mn;
      }

  // combine the two column-half waves via LDS (alias onto As/Bs — done with tiles)
  float* cm = reinterpret_cast<float*>(As);   // [2][BM]
  float* cl = reinterpret_cast<float*>(Bs);   // [2][BM]
  __syncthreads();
  if (l15 == 0) {
#pragma unroll
    for (int mt = 0; mt < 4; ++mt)
#pragma unroll
      for (int r = 0; r < 4; ++r) {
        int rl = wm * 64 + mt * 16 + l4 * 4 + r;
        cm[wn * BM + rl] = mrun[mt][r];
        cl[wn * BM + rl] = lrun[mt][r];
      }
  }
  __syncthreads();
  if (tid < BM) {
    float m0 = cm[tid], l0 = cl[tid];
    float m1 = cm[BM + tid], l1 = cl[BM + tid];
    float mn = fmaxf(m0, m1);
    float ll = l0 * __expf(m0 - mn) + l1 * __expf(m1 - mn);
    size_t g = (size_t)(rb * BM + tid) * NPART + cp;
    pm[g] = mn;
    pl[g] = ll;
  }
}

// ---------------- combine partitions, subtract diag, mean -> loss ----------------
__global__ void loss_kernel(const float* __restrict__ pm, const float* __restrict__ pl,
                            const float* __restrict__ dg, float* __restrict__ out) {
  __shared__ float red[1024];
  int tid = threadIdx.x;
  float local = 0.f;
  for (int j = 0; j < BS / 1024; ++j) {
    int r = tid + j * 1024;
    float m = -1e30f, l = 0.f;
#pragma unroll
    for (int p = 0; p < NPART; ++p) {
      float m2 = pm[(size_t)r * NPART + p];
      float l2 = pl[(size_t)r * NPART + p];
      float mn = fmaxf(m, m2);
      l = l * __expf(m - mn) + l2 * __expf(m2 - mn);
      m = mn;
    }
    local += m + __logf(l) - dg[r];
  }
  red[tid] = local;
  __syncthreads();
  for (int s = 512; s; s >>= 1) {
    if (tid < s) red[tid] += red[tid + s];
    __syncthreads();
  }
  if (tid == 0) out[0] = red[0] / (float)BS;
}

extern "C" void kernel_launch(void* const* d_in, const int* in_sizes, int n_in,
                              void* d_out, int out_size, void* d_ws, size_t ws_size,
                              hipStream_t stream) {
  const float* nl = (const float*)d_in[0];
  const float* cd = (const float*)d_in[1];
  float* out = (float*)d_out;

  const size_t NEL = (size_t)BS * DIM;

  unsigned short* nlb = (unsigned short*)d_ws;       // NEL bf16
  unsigned short* cdb = nlb + NEL;                   // NEL bf16
  float* pm = (float*)(cdb + NEL);                   // BS*NPART
  float* pl = pm + (size_t)BS * NPART;               // BS*NPART
  float* dg = pl + (size_t)BS * NPART;               // BS

  // outputs: [loss, code_vec copy, nl_vec copy]; copies fused with bf16 convert
  prep_kernel<<<NEL / 4 / 256, 256, 0, stream>>>(cd, out + 1, cdb);
  prep_kernel<<<NEL / 4 / 256, 256, 0, stream>>>(nl, out + 1 + NEL, nlb);
  diag_kernel<<<BS / 4, 256, 0, stream>>>(nl, cd, dg);
  gemm_lse_kernel<<<dim3(NPART, BS / BM), 256, 0, stream>>>(nlb, cdb, pm, pl);
  loss_kernel<<<1, 1024, 0, stream>>>(pm, pl, dg, out);
}

// Round 3
// 242.307 us; speedup vs baseline: 1.4274x; 1.0275x over previous
//
#include <hip/hip_runtime.h>

#define BS     8192
#define DIM    768
#define NPART  16
#define BM     128
#define BN     128
#define BK     64
#define PCOLS  (BS / NPART)     // 512 cols per partition
#define NJT    (PCOLS / BN)     // 4 col-tiles per block
#define NKT    (DIM / BK)       // 12 k-tiles

typedef __bf16 bfrag_t __attribute__((ext_vector_type(8)));
typedef float  facc_t  __attribute__((ext_vector_type(4)));

typedef const __attribute__((address_space(1))) void gv_t;
typedef __attribute__((address_space(3))) void lv_t;

__device__ __forceinline__ void gll16(const void* g, void* l) {
  // async global->LDS DMA, 16B/lane; LDS dest = wave-uniform base + lane*16
  __builtin_amdgcn_global_load_lds((gv_t*)g, (lv_t*)l, 16, 0, 0);
}

__device__ __forceinline__ unsigned short f2bf(float f) {
  union { float f; unsigned u; } v; v.f = f;
  unsigned u = v.u;
  return (unsigned short)((u + 0x7FFFu + ((u >> 16) & 1u)) >> 16);  // RNE
}

// ---------------- fused: fp32 copy-out (both), bf16 convert (both), diag ----------------
// One wave per row: read nl[row], cd[row] once each (3 float4/lane),
// write fp32 copies to out, bf16 rows to ws, diag dot via shuffle.
__global__ void prep_kernel(const float* __restrict__ nl, const float* __restrict__ cd,
                            float* __restrict__ cd_copy, float* __restrict__ nl_copy,
                            unsigned short* __restrict__ nlb, unsigned short* __restrict__ cdb,
                            float* __restrict__ dg) {
  const int lane = threadIdx.x & 63;
  const int wave = threadIdx.x >> 6;
  const int row  = blockIdx.x * 4 + wave;
  const size_t rbase = (size_t)row * DIM;
  const float4* ar = reinterpret_cast<const float4*>(nl + rbase);
  const float4* br = reinterpret_cast<const float4*>(cd + rbase);
  float4* wa = reinterpret_cast<float4*>(nl_copy + rbase);
  float4* wb = reinterpret_cast<float4*>(cd_copy + rbase);
  ushort4* ba = reinterpret_cast<ushort4*>(nlb + rbase);
  ushort4* bb = reinterpret_cast<ushort4*>(cdb + rbase);

  float s = 0.f;
#pragma unroll
  for (int i = 0; i < 3; ++i) {                 // 192 float4 per row, 3 per lane
    int idx = lane + 64 * i;
    float4 x = ar[idx];
    float4 y = br[idx];
    wa[idx] = x;
    wb[idx] = y;
    ushort4 xb, yb;
    xb.x = f2bf(x.x); xb.y = f2bf(x.y); xb.z = f2bf(x.z); xb.w = f2bf(x.w);
    yb.x = f2bf(y.x); yb.y = f2bf(y.y); yb.z = f2bf(y.z); yb.w = f2bf(y.w);
    ba[idx] = xb;
    bb[idx] = yb;
    s += x.x * y.x + x.y * y.y + x.z * y.z + x.w * y.w;
  }
#pragma unroll
  for (int off = 32; off; off >>= 1) s += __shfl_xor(s, off, 64);
  if (lane == 0) dg[row] = s;
}

// ---------------- fused GEMM (bf16 MFMA, global_load_lds staging) + online lse ----------------
// block: 256 threads (4 waves, 2x2 of 64x64), tile 128x128, BK=64.
// grid: (NPART, BS/BM) = (16, 64) = 1024 blocks = 4/CU.
// LDS: XOR-swizzled, unpadded (required by global_load_lds):
//   unit u (16B = 8 bf16) holds global (row=u>>3, c8 = (u&7)^(row&7)).
__global__ __launch_bounds__(256, 4) void gemm_lse_kernel(
    const unsigned short* __restrict__ Abf,
    const unsigned short* __restrict__ Bbf,
    float* __restrict__ pm, float* __restrict__ pl) {
  __shared__ __align__(16) unsigned short As[BM * BK];   // 16 KB
  __shared__ __align__(16) unsigned short Bs[BN * BK];   // 16 KB

  const int tid  = threadIdx.x;
  const int lane = tid & 63;
  const int wave = tid >> 6;
  const int wm   = wave >> 1;
  const int wn   = wave & 1;
  const int l15  = lane & 15;
  const int l4   = lane >> 4;
  const int sw   = l15 & 7;        // row-dependent xor for fragment reads
  const int cp   = blockIdx.x;
  const int rb   = blockIdx.y;

  // staging geometry (kt-invariant): per instr t, u = wave*256 + t*64 + lane
  int srow[4], sc8g[4];
#pragma unroll
  for (int t = 0; t < 4; ++t) {
    int u   = wave * 256 + t * 64 + lane;
    srow[t] = u >> 3;
    sc8g[t] = (u & 7) ^ (srow[t] & 7);
  }

  float mrun[4][4], lrun[4][4];
#pragma unroll
  for (int i = 0; i < 4; ++i)
#pragma unroll
    for (int r = 0; r < 4; ++r) { mrun[i][r] = -1e30f; lrun[i][r] = 0.f; }

  for (int jt = 0; jt < NJT; ++jt) {
    facc_t acc[4][4];
#pragma unroll
    for (int mt = 0; mt < 4; ++mt)
#pragma unroll
      for (int nt = 0; nt < 4; ++nt) acc[mt][nt] = (facc_t){0.f, 0.f, 0.f, 0.f};

    for (int kt = 0; kt < NKT; ++kt) {
      __syncthreads();
#pragma unroll
      for (int t = 0; t < 4; ++t) {
        size_t ldso = (size_t)(wave * 256 + t * 64) * 8;  // shorts
        gll16(Abf + (size_t)(rb * BM + srow[t]) * DIM + kt * BK + sc8g[t] * 8, As + ldso);
        gll16(Bbf + (size_t)(cp * PCOLS + jt * BN + srow[t]) * DIM + kt * BK + sc8g[t] * 8, Bs + ldso);
      }
      __syncthreads();

#pragma unroll
      for (int ks = 0; ks < 2; ++ks) {
        const int k8 = ks * 4 + l4;
        bfrag_t af[4], bfv[4];
#pragma unroll
        for (int mt = 0; mt < 4; ++mt) {
          int row = wm * 64 + mt * 16 + l15;
          af[mt] = *reinterpret_cast<const bfrag_t*>(&As[row * BK + (k8 ^ sw) * 8]);
        }
#pragma unroll
        for (int nt = 0; nt < 4; ++nt) {
          int row = wn * 64 + nt * 16 + l15;
          bfv[nt] = *reinterpret_cast<const bfrag_t*>(&Bs[row * BK + (k8 ^ sw) * 8]);
        }
#pragma unroll
        for (int mt = 0; mt < 4; ++mt)
#pragma unroll
          for (int nt = 0; nt < 4; ++nt)
            acc[mt][nt] = __builtin_amdgcn_mfma_f32_16x16x32_bf16(af[mt], bfv[nt], acc[mt][nt], 0, 0, 0);
      }
    }

    // online-lse update (per lane over its own column subset)
#pragma unroll
    for (int mt = 0; mt < 4; ++mt)
#pragma unroll
      for (int r = 0; r < 4; ++r) {
        float v0 = acc[mt][0][r], v1 = acc[mt][1][r], v2 = acc[mt][2][r], v3 = acc[mt][3][r];
        float tm = fmaxf(fmaxf(v0, v1), fmaxf(v2, v3));
        float mn = fmaxf(mrun[mt][r], tm);
        float sc = __expf(mrun[mt][r] - mn);
        lrun[mt][r] = lrun[mt][r] * sc +
                      __expf(v0 - mn) + __expf(v1 - mn) + __expf(v2 - mn) + __expf(v3 - mn);
        mrun[mt][r] = mn;
      }
  }

  // merge across the 16 lanes sharing rows (different column subsets)
#pragma unroll
  for (int mask = 1; mask < 16; mask <<= 1)
#pragma unroll
    for (int mt = 0; mt < 4; ++mt)
#pragma unroll
      for (int r = 0; r < 4; ++r) {
        float om = __shfl_xor(mrun[mt][r], mask, 64);
        float ol = __shfl_xor(lrun[mt][r], mask, 64);
        float mn = fmaxf(mrun[mt][r], om);
        lrun[mt][r] = lrun[mt][r] * __expf(mrun[mt][r] - mn) + ol * __expf(om - mn);
        mrun[mt][r] = mn;
      }

  // combine the two column-half waves via LDS (alias onto As/Bs — done with tiles)
  float* cm = reinterpret_cast<float*>(As);   // [2][BM]
  float* cl = reinterpret_cast<float*>(Bs);   // [2][BM]
  __syncthreads();
  if (l15 == 0) {
#pragma unroll
    for (int mt = 0; mt < 4; ++mt)
#pragma unroll
      for (int r = 0; r < 4; ++r) {
        int rl = wm * 64 + mt * 16 + l4 * 4 + r;
        cm[wn * BM + rl] = mrun[mt][r];
        cl[wn * BM + rl] = lrun[mt][r];
      }
  }
  __syncthreads();
  if (tid < BM) {
    float m0 = cm[tid], l0 = cl[tid];
    float m1 = cm[BM + tid], l1 = cl[BM + tid];
    float mn = fmaxf(m0, m1);
    float ll = l0 * __expf(m0 - mn) + l1 * __expf(m1 - mn);
    size_t g = (size_t)(rb * BM + tid) * NPART + cp;
    pm[g] = mn;
    pl[g] = ll;
  }
}

// ---------------- combine partitions, subtract diag, mean -> loss ----------------
__global__ void loss_kernel(const float* __restrict__ pm, const float* __restrict__ pl,
                            const float* __restrict__ dg, float* __restrict__ out) {
  __shared__ float red[1024];
  int tid = threadIdx.x;
  float local = 0.f;
  for (int j = 0; j < BS / 1024; ++j) {
    int r = tid + j * 1024;
    float m = -1e30f, l = 0.f;
#pragma unroll
    for (int p = 0; p < NPART; ++p) {
      float m2 = pm[(size_t)r * NPART + p];
      float l2 = pl[(size_t)r * NPART + p];
      float mn = fmaxf(m, m2);
      l = l * __expf(m - mn) + l2 * __expf(m2 - mn);
      m = mn;
    }
    local += m + __logf(l) - dg[r];
  }
  red[tid] = local;
  __syncthreads();
  for (int s = 512; s; s >>= 1) {
    if (tid < s) red[tid] += red[tid + s];
    __syncthreads();
  }
  if (tid == 0) out[0] = red[0] / (float)BS;
}

extern "C" void kernel_launch(void* const* d_in, const int* in_sizes, int n_in,
                              void* d_out, int out_size, void* d_ws, size_t ws_size,
                              hipStream_t stream) {
  const float* nl = (const float*)d_in[0];
  const float* cd = (const float*)d_in[1];
  float* out = (float*)d_out;

  const size_t NEL = (size_t)BS * DIM;

  unsigned short* nlb = (unsigned short*)d_ws;       // NEL bf16
  unsigned short* cdb = nlb + NEL;                   // NEL bf16
  float* pm = (float*)(cdb + NEL);                   // BS*NPART
  float* pl = pm + (size_t)BS * NPART;               // BS*NPART
  float* dg = pl + (size_t)BS * NPART;               // BS

  // out = [loss, code_vec copy, nl_vec copy]
  prep_kernel<<<BS / 4, 256, 0, stream>>>(nl, cd, out + 1, out + 1 + NEL, nlb, cdb, dg);
  gemm_lse_kernel<<<dim3(NPART, BS / BM), 256, 0, stream>>>(nlb, cdb, pm, pl);
  loss_kernel<<<1, 1024, 0, stream>>>(pm, pl, dg, out);
}

// Round 4
// 226.476 us; speedup vs baseline: 1.5272x; 1.0699x over previous
//
#include <hip/hip_runtime.h>

#define BS     8192
#define DIM    768
#define NPART  16
#define BM     128
#define BN     128
#define BK     64
#define PCOLS  (BS / NPART)     // 512 cols per partition
#define NJT    (PCOLS / BN)     // 4 col-tiles per block
#define NKT    (DIM / BK)       // 12 k-tiles
#define L1B    128              // loss stage-1 blocks
#define L1R    (BS / L1B)       // rows per stage-1 block (64)

typedef __bf16 bfrag_t __attribute__((ext_vector_type(8)));
typedef float  facc_t  __attribute__((ext_vector_type(4)));

typedef const __attribute__((address_space(1))) void gv_t;
typedef __attribute__((address_space(3))) void lv_t;

__device__ __forceinline__ void gll16(const void* g, void* l) {
  // async global->LDS DMA, 16B/lane; LDS dest = wave-uniform base + lane*16
  __builtin_amdgcn_global_load_lds((gv_t*)g, (lv_t*)l, 16, 0, 0);
}

__device__ __forceinline__ unsigned short f2bf(float f) {
  union { float f; unsigned u; } v; v.f = f;
  unsigned u = v.u;
  return (unsigned short)((u + 0x7FFFu + ((u >> 16) & 1u)) >> 16);  // RNE
}

// ---------------- fused: fp32 copy-out (both), bf16 convert (both), diag ----------------
__global__ void prep_kernel(const float* __restrict__ nl, const float* __restrict__ cd,
                            float* __restrict__ cd_copy, float* __restrict__ nl_copy,
                            unsigned short* __restrict__ nlb, unsigned short* __restrict__ cdb,
                            float* __restrict__ dg) {
  const int lane = threadIdx.x & 63;
  const int wave = threadIdx.x >> 6;
  const int row  = blockIdx.x * 4 + wave;
  const size_t rbase = (size_t)row * DIM;
  const float4* ar = reinterpret_cast<const float4*>(nl + rbase);
  const float4* br = reinterpret_cast<const float4*>(cd + rbase);
  float4* wa = reinterpret_cast<float4*>(nl_copy + rbase);
  float4* wb = reinterpret_cast<float4*>(cd_copy + rbase);
  ushort4* ba = reinterpret_cast<ushort4*>(nlb + rbase);
  ushort4* bb = reinterpret_cast<ushort4*>(cdb + rbase);

  float s = 0.f;
#pragma unroll
  for (int i = 0; i < 3; ++i) {                 // 192 float4 per row, 3 per lane
    int idx = lane + 64 * i;
    float4 x = ar[idx];
    float4 y = br[idx];
    wa[idx] = x;
    wb[idx] = y;
    ushort4 xb, yb;
    xb.x = f2bf(x.x); xb.y = f2bf(x.y); xb.z = f2bf(x.z); xb.w = f2bf(x.w);
    yb.x = f2bf(y.x); yb.y = f2bf(y.y); yb.z = f2bf(y.z); yb.w = f2bf(y.w);
    ba[idx] = xb;
    bb[idx] = yb;
    s += x.x * y.x + x.y * y.y + x.z * y.z + x.w * y.w;
  }
#pragma unroll
  for (int off = 32; off; off >>= 1) s += __shfl_xor(s, off, 64);
  if (lane == 0) dg[row] = s;
}

// ---------------- fused GEMM (bf16 MFMA, global_load_lds staging) + online lse ----------------
// block: 256 threads (4 waves, 2x2 of 64x64), tile 128x128, BK=64.
// grid: (NPART, BS/BM) = (16, 64) = 1024 blocks.
// LDS: XOR-swizzled, unpadded (required by global_load_lds):
//   unit u (16B = 8 bf16) holds global (row=u>>3, c8 = (u&7)^(row&7)).
__global__ __launch_bounds__(256, 4) void gemm_lse_kernel(
    const unsigned short* __restrict__ Abf,
    const unsigned short* __restrict__ Bbf,
    float* __restrict__ pm, float* __restrict__ pl) {
  __shared__ __align__(16) unsigned short As[BM * BK];   // 16 KB
  __shared__ __align__(16) unsigned short Bs[BN * BK];   // 16 KB

  const int tid  = threadIdx.x;
  const int lane = tid & 63;
  const int wave = tid >> 6;
  const int wm   = wave >> 1;
  const int wn   = wave & 1;
  const int l15  = lane & 15;
  const int l4   = lane >> 4;
  const int sw   = l15 & 7;        // row-dependent xor for fragment reads
  const int cp   = blockIdx.x;
  const int rb   = blockIdx.y;

  int srow[4], sc8g[4];
#pragma unroll
  for (int t = 0; t < 4; ++t) {
    int u   = wave * 256 + t * 64 + lane;
    srow[t] = u >> 3;
    sc8g[t] = (u & 7) ^ (srow[t] & 7);
  }

  float mrun[4][4], lrun[4][4];
#pragma unroll
  for (int i = 0; i < 4; ++i)
#pragma unroll
    for (int r = 0; r < 4; ++r) { mrun[i][r] = -1e30f; lrun[i][r] = 0.f; }

  for (int jt = 0; jt < NJT; ++jt) {
    facc_t acc[4][4];
#pragma unroll
    for (int mt = 0; mt < 4; ++mt)
#pragma unroll
      for (int nt = 0; nt < 4; ++nt) acc[mt][nt] = (facc_t){0.f, 0.f, 0.f, 0.f};

    for (int kt = 0; kt < NKT; ++kt) {
      __syncthreads();
#pragma unroll
      for (int t = 0; t < 4; ++t) {
        size_t ldso = (size_t)(wave * 256 + t * 64) * 8;  // shorts
        gll16(Abf + (size_t)(rb * BM + srow[t]) * DIM + kt * BK + sc8g[t] * 8, As + ldso);
        gll16(Bbf + (size_t)(cp * PCOLS + jt * BN + srow[t]) * DIM + kt * BK + sc8g[t] * 8, Bs + ldso);
      }
      __syncthreads();

#pragma unroll
      for (int ks = 0; ks < 2; ++ks) {
        const int k8 = ks * 4 + l4;
        bfrag_t af[4], bfv[4];
#pragma unroll
        for (int mt = 0; mt < 4; ++mt) {
          int row = wm * 64 + mt * 16 + l15;
          af[mt] = *reinterpret_cast<const bfrag_t*>(&As[row * BK + (k8 ^ sw) * 8]);
        }
#pragma unroll
        for (int nt = 0; nt < 4; ++nt) {
          int row = wn * 64 + nt * 16 + l15;
          bfv[nt] = *reinterpret_cast<const bfrag_t*>(&Bs[row * BK + (k8 ^ sw) * 8]);
        }
#pragma unroll
        for (int mt = 0; mt < 4; ++mt)
#pragma unroll
          for (int nt = 0; nt < 4; ++nt)
            acc[mt][nt] = __builtin_amdgcn_mfma_f32_16x16x32_bf16(af[mt], bfv[nt], acc[mt][nt], 0, 0, 0);
      }
    }

    // online-lse update (per lane over its own column subset)
#pragma unroll
    for (int mt = 0; mt < 4; ++mt)
#pragma unroll
      for (int r = 0; r < 4; ++r) {
        float v0 = acc[mt][0][r], v1 = acc[mt][1][r], v2 = acc[mt][2][r], v3 = acc[mt][3][r];
        float tm = fmaxf(fmaxf(v0, v1), fmaxf(v2, v3));
        float mn = fmaxf(mrun[mt][r], tm);
        float sc = __expf(mrun[mt][r] - mn);
        lrun[mt][r] = lrun[mt][r] * sc +
                      __expf(v0 - mn) + __expf(v1 - mn) + __expf(v2 - mn) + __expf(v3 - mn);
        mrun[mt][r] = mn;
      }
  }

  // merge across the 16 lanes sharing rows (different column subsets)
#pragma unroll
  for (int mask = 1; mask < 16; mask <<= 1)
#pragma unroll
    for (int mt = 0; mt < 4; ++mt)
#pragma unroll
      for (int r = 0; r < 4; ++r) {
        float om = __shfl_xor(mrun[mt][r], mask, 64);
        float ol = __shfl_xor(lrun[mt][r], mask, 64);
        float mn = fmaxf(mrun[mt][r], om);
        lrun[mt][r] = lrun[mt][r] * __expf(mrun[mt][r] - mn) + ol * __expf(om - mn);
        mrun[mt][r] = mn;
      }

  // combine the two column-half waves via LDS (alias onto As/Bs — done with tiles)
  float* cm = reinterpret_cast<float*>(As);   // [2][BM]
  float* cl = reinterpret_cast<float*>(Bs);   // [2][BM]
  __syncthreads();
  if (l15 == 0) {
#pragma unroll
    for (int mt = 0; mt < 4; ++mt)
#pragma unroll
      for (int r = 0; r < 4; ++r) {
        int rl = wm * 64 + mt * 16 + l4 * 4 + r;
        cm[wn * BM + rl] = mrun[mt][r];
        cl[wn * BM + rl] = lrun[mt][r];
      }
  }
  __syncthreads();
  if (tid < BM) {
    float m0 = cm[tid], l0 = cl[tid];
    float m1 = cm[BM + tid], l1 = cl[BM + tid];
    float mn = fmaxf(m0, m1);
    float ll = l0 * __expf(m0 - mn) + l1 * __expf(m1 - mn);
    size_t g = (size_t)(rb * BM + tid) * NPART + cp;
    pm[g] = mn;
    pl[g] = ll;
  }
}

// ---------------- loss stage 1: 128 blocks x 64 rows, partial sums ----------------
__global__ void loss_stage1_kernel(const float* __restrict__ pm, const float* __restrict__ pl,
                                   const float* __restrict__ dg, float* __restrict__ partial) {
  __shared__ float red[64];
  const int tid = threadIdx.x;        // 64 threads, one row each
  const int r   = blockIdx.x * L1R + tid;

  const float4* pmr = reinterpret_cast<const float4*>(pm + (size_t)r * NPART);
  const float4* plr = reinterpret_cast<const float4*>(pl + (size_t)r * NPART);

  float m = -1e30f, l = 0.f;
#pragma unroll
  for (int q = 0; q < NPART / 4; ++q) {
    float4 mv = pmr[q];
    float4 lv = plr[q];
#pragma unroll
    for (int k = 0; k < 4; ++k) {
      float m2 = (&mv.x)[k], l2 = (&lv.x)[k];
      float mn = fmaxf(m, m2);
      l = l * __expf(m - mn) + l2 * __expf(m2 - mn);
      m = mn;
    }
  }
  float local = m + __logf(l) - dg[r];

  // wave reduce (64 threads = 1 wave)
#pragma unroll
  for (int off = 32; off; off >>= 1) local += __shfl_xor(local, off, 64);
  if (tid == 0) partial[blockIdx.x] = local;
  (void)red;
}

// ---------------- loss stage 2: reduce 128 partials -> loss ----------------
__global__ void loss_stage2_kernel(const float* __restrict__ partial, float* __restrict__ out) {
  const int tid = threadIdx.x;        // 128 threads
  float v = partial[tid];
#pragma unroll
  for (int off = 32; off; off >>= 1) v += __shfl_xor(v, off, 64);
  __shared__ float red[2];
  if ((tid & 63) == 0) red[tid >> 6] = v;
  __syncthreads();
  if (tid == 0) out[0] = (red[0] + red[1]) / (float)BS;
}

extern "C" void kernel_launch(void* const* d_in, const int* in_sizes, int n_in,
                              void* d_out, int out_size, void* d_ws, size_t ws_size,
                              hipStream_t stream) {
  const float* nl = (const float*)d_in[0];
  const float* cd = (const float*)d_in[1];
  float* out = (float*)d_out;

  const size_t NEL = (size_t)BS * DIM;

  unsigned short* nlb = (unsigned short*)d_ws;       // NEL bf16
  unsigned short* cdb = nlb + NEL;                   // NEL bf16
  float* pm = (float*)(cdb + NEL);                   // BS*NPART
  float* pl = pm + (size_t)BS * NPART;               // BS*NPART
  float* dg = pl + (size_t)BS * NPART;               // BS
  float* partial = dg + BS;                          // L1B

  // out = [loss, code_vec copy, nl_vec copy]
  prep_kernel<<<BS / 4, 256, 0, stream>>>(nl, cd, out + 1, out + 1 + NEL, nlb, cdb, dg);
  gemm_lse_kernel<<<dim3(NPART, BS / BM), 256, 0, stream>>>(nlb, cdb, pm, pl);
  loss_stage1_kernel<<<L1B, 64, 0, stream>>>(pm, pl, dg, partial);
  loss_stage2_kernel<<<1, 128, 0, stream>>>(partial, out);
}